// Round 1
// baseline (856.720 us; speedup 1.0000x reference)
//
#include <hip/hip_runtime.h>
#include <math.h>
#include <stdint.h>

#define N_NODES 100000
#define N_EDGES 1600000
#define N_GRAPHS 64

// ---------------- workspace layout (bytes) ----------------
// cnt      @ 0         : 100000 int   (400000)
// fill     @ 400128    : 100000 int
// inv_cnt  @ 800256    : 100000 float
// row_ptr  @ 1200384   : 100001 int
// col      @ 1600512   : 1600000 int  (6.4 MB)
// pooled   @ 8000512   : 64*64 float
// h1       @ 8016896   : 100000*64 float (25.6 MB)
// h2       @ 33616896  : 100000*64 float (25.6 MB)
// bsum     @ 59216896  : 128 int
// total ~59.3 MB

__device__ __forceinline__ void atomicMaxFloat(float* addr, float val) {
    if (val >= 0.0f) {
        atomicMax((int*)addr, __float_as_int(val));
    } else {
        atomicMin((unsigned int*)addr, __float_as_uint(val));
    }
}

__global__ void k_init(int* __restrict__ cnt, int* __restrict__ fill,
                       float* __restrict__ pooled) {
    int i = blockIdx.x * blockDim.x + threadIdx.x;
    if (i < N_NODES) { cnt[i] = 0; fill[i] = 0; }
    if (i < N_GRAPHS * 64) pooled[i] = -INFINITY;
}

__global__ void k_hist(const int* __restrict__ dst, int* __restrict__ cnt) {
    int e = blockIdx.x * blockDim.x + threadIdx.x;
    if (e < N_EDGES) atomicAdd(&cnt[dst[e]], 1);
}

#define SCAN_CHUNK 1024

__global__ void k_scan1(const int* __restrict__ cnt, int* __restrict__ bsum) {
    __shared__ int lds[256];
    int b = blockIdx.x, t = threadIdx.x;
    int base = b * SCAN_CHUNK + t * 4;
    int s = 0;
#pragma unroll
    for (int j = 0; j < 4; ++j) {
        int i = base + j;
        if (i < N_NODES) s += cnt[i];
    }
    lds[t] = s;
    __syncthreads();
    for (int off = 128; off > 0; off >>= 1) {
        if (t < off) lds[t] += lds[t + off];
        __syncthreads();
    }
    if (t == 0) bsum[b] = lds[0];
}

__global__ void k_scan2(int* __restrict__ bsum, int nb) {
    if (threadIdx.x == 0 && blockIdx.x == 0) {
        int acc = 0;
        for (int i = 0; i < nb; ++i) { int v = bsum[i]; bsum[i] = acc; acc += v; }
    }
}

__global__ void k_scan3(const int* __restrict__ cnt, const int* __restrict__ bsum,
                        int* __restrict__ row_ptr) {
    __shared__ int lds[256];
    int b = blockIdx.x, t = threadIdx.x;
    int base = b * SCAN_CHUNK + t * 4;
    int v[4];
    int s = 0;
#pragma unroll
    for (int j = 0; j < 4; ++j) {
        int i = base + j;
        v[j] = (i < N_NODES) ? cnt[i] : 0;
        s += v[j];
    }
    lds[t] = s;
    __syncthreads();
    for (int off = 1; off < 256; off <<= 1) {
        int add = (t >= off) ? lds[t - off] : 0;
        __syncthreads();
        lds[t] += add;
        __syncthreads();
    }
    int ex = bsum[b] + ((t > 0) ? lds[t - 1] : 0);
#pragma unroll
    for (int j = 0; j < 4; ++j) {
        int i = base + j;
        if (i < N_NODES) { ex += v[j]; row_ptr[i + 1] = ex; }
    }
    if (b == 0 && t == 0) row_ptr[0] = 0;
}

__global__ void k_inv(const int* __restrict__ cnt, float* __restrict__ inv) {
    int i = blockIdx.x * blockDim.x + threadIdx.x;
    if (i < N_NODES) inv[i] = (cnt[i] > 0) ? (1.0f / (float)cnt[i]) : 0.0f;
}

__global__ void k_fill(const int* __restrict__ src, const int* __restrict__ dst,
                       const int* __restrict__ row_ptr, int* __restrict__ fill,
                       int* __restrict__ col) {
    int e = blockIdx.x * blockDim.x + threadIdx.x;
    if (e < N_EDGES) {
        int d = dst[e];
        int pos = atomicAdd(&fill[d], 1);
        col[row_ptr[d] + pos] = src[e];
    }
}

// Fused SAGE layer: out = (segsum(h[src])/cnt) @ Wl + bl + h @ Wr
// One wave per node. lane = output feature (64 outputs).
template <int FIN>
__global__ __launch_bounds__(256) void k_sage(
    const float* __restrict__ h, const int* __restrict__ row_ptr,
    const int* __restrict__ col, const float* __restrict__ inv_cnt,
    const float* __restrict__ Wl, const float* __restrict__ bl,
    const float* __restrict__ Wr, float* __restrict__ out) {
    __shared__ float wl[FIN * 64];
    __shared__ float wr[FIN * 64];
    for (int i = threadIdx.x; i < FIN * 64 / 4; i += 256) {
        ((float4*)wl)[i] = ((const float4*)Wl)[i];
        ((float4*)wr)[i] = ((const float4*)Wr)[i];
    }
    __syncthreads();

    int lane = threadIdx.x & 63;
    int wave = blockIdx.x * 4 + (threadIdx.x >> 6);
    int nWaves = gridDim.x * 4;
    float blf = bl[lane];

    for (int node = wave; node < N_NODES; node += nWaves) {
        int start = __builtin_amdgcn_readfirstlane(row_ptr[node]);
        int end   = __builtin_amdgcn_readfirstlane(row_ptr[node + 1]);
        float s = 0.0f;
        float xr = 0.0f;

        if constexpr (FIN == 64) {
            xr = h[(size_t)node * 64 + lane];
            for (int base = start; base < end; base += 64) {
                int n = end - base; if (n > 64) n = 64;
                int cb = (base + lane < end) ? col[base + lane] : 0;
                int j = 0;
                for (; j + 3 < n; j += 4) {
                    int c0 = __shfl(cb, j), c1 = __shfl(cb, j + 1);
                    int c2 = __shfl(cb, j + 2), c3 = __shfl(cb, j + 3);
                    float a0 = h[(size_t)c0 * 64 + lane];
                    float a1 = h[(size_t)c1 * 64 + lane];
                    float a2 = h[(size_t)c2 * 64 + lane];
                    float a3 = h[(size_t)c3 * 64 + lane];
                    s += (a0 + a1) + (a2 + a3);
                }
                for (; j < n; ++j) {
                    int c = __shfl(cb, j);
                    s += h[(size_t)c * 64 + lane];
                }
            }
        } else {  // FIN == 32: lanes 0-31 even edges, 32-63 odd edges
            int k = lane & 31;
            int half = lane >> 5;
            if (lane < 32) xr = h[(size_t)node * 32 + lane];
            for (int e = start + half; e < end; e += 2) {
                int c = col[e];
                s += h[(size_t)c * 32 + k];
            }
            s += __shfl_xor(s, 32);  // every lane now has total for feature (lane&31)
        }

        float mean = s * inv_cnt[node];
        float acc = blf;
#pragma unroll
        for (int kk = 0; kk < FIN; ++kk) {
            float mk = __shfl(mean, kk);
            float xk = __shfl(xr, kk);
            acc += mk * wl[kk * 64 + lane] + xk * wr[kk * 64 + lane];
        }
        out[(size_t)node * 64 + lane] = acc;
    }
}

__global__ __launch_bounds__(256) void k_pool(const float* __restrict__ h,
                                              const int* __restrict__ batch,
                                              float* __restrict__ pooled) {
    int lane = threadIdx.x & 63;
    int wave = (blockIdx.x * blockDim.x + threadIdx.x) >> 6;
    int nWaves = (gridDim.x * blockDim.x) >> 6;
    int per = (N_NODES + nWaves - 1) / nWaves;
    int beg = wave * per;
    int end = beg + per; if (end > N_NODES) end = N_NODES;
    if (beg >= end) return;
    int curg = batch[beg];
    float m = -INFINITY;
    for (int i = beg; i < end; ++i) {
        int g = batch[i];
        if (g != curg) {
            atomicMaxFloat(&pooled[curg * 64 + lane], m);
            m = -INFINITY;
            curg = g;
        }
        m = fmaxf(m, h[(size_t)i * 64 + lane]);
    }
    atomicMaxFloat(&pooled[curg * 64 + lane], m);
}

__global__ void k_head(const float* __restrict__ pooled,
                       const float* __restrict__ Wout,
                       const float* __restrict__ bout, float* __restrict__ out) {
    int tid = threadIdx.x;          // 512 threads: g = tid>>3, o = tid&7
    int g = tid >> 3, o = tid & 7;
    float acc = bout[o];
#pragma unroll
    for (int k = 0; k < 64; ++k) acc += pooled[g * 64 + k] * Wout[k * 8 + o];
    float mx = acc;
#pragma unroll
    for (int m = 1; m < 8; m <<= 1) mx = fmaxf(mx, __shfl_xor(mx, m));
    float ex = expf(acc - mx);
    float sum = ex;
#pragma unroll
    for (int m = 1; m < 8; m <<= 1) sum += __shfl_xor(sum, m);
    out[g * 8 + o] = (acc - mx) - logf(sum);
}

extern "C" void kernel_launch(void* const* d_in, const int* in_sizes, int n_in,
                              void* d_out, int out_size, void* d_ws, size_t ws_size,
                              hipStream_t stream) {
    const float* x    = (const float*)d_in[0];
    const float* Wl0  = (const float*)d_in[1];
    const float* bl0  = (const float*)d_in[2];
    const float* Wr0  = (const float*)d_in[3];
    const float* Wl1  = (const float*)d_in[4];
    const float* bl1  = (const float*)d_in[5];
    const float* Wr1  = (const float*)d_in[6];
    const float* Wl2  = (const float*)d_in[7];
    const float* bl2  = (const float*)d_in[8];
    const float* Wr2  = (const float*)d_in[9];
    const float* Wout = (const float*)d_in[10];
    const float* bout = (const float*)d_in[11];
    const int*   eidx = (const int*)d_in[12];
    const int*   batch= (const int*)d_in[13];
    const int* src = eidx;
    const int* dst = eidx + N_EDGES;

    uint8_t* ws = (uint8_t*)d_ws;
    int*   cnt     = (int*)(ws + 0);
    int*   fill    = (int*)(ws + 400128);
    float* inv     = (float*)(ws + 800256);
    int*   row_ptr = (int*)(ws + 1200384);
    int*   col     = (int*)(ws + 1600512);
    float* pooled  = (float*)(ws + 8000512);
    float* h1      = (float*)(ws + 8016896);
    float* h2      = (float*)(ws + 33616896);
    int*   bsum    = (int*)(ws + 59216896);

    int nb = (N_NODES + SCAN_CHUNK - 1) / SCAN_CHUNK;  // 98

    k_init<<<(N_NODES + 255) / 256, 256, 0, stream>>>(cnt, fill, pooled);
    k_hist<<<(N_EDGES + 255) / 256, 256, 0, stream>>>(dst, cnt);
    k_scan1<<<nb, 256, 0, stream>>>(cnt, bsum);
    k_scan2<<<1, 64, 0, stream>>>(bsum, nb);
    k_scan3<<<nb, 256, 0, stream>>>(cnt, bsum, row_ptr);
    k_inv<<<(N_NODES + 255) / 256, 256, 0, stream>>>(cnt, inv);
    k_fill<<<(N_EDGES + 255) / 256, 256, 0, stream>>>(src, dst, row_ptr, fill, col);

    k_sage<32><<<2048, 256, 0, stream>>>(x,  row_ptr, col, inv, Wl0, bl0, Wr0, h1);
    k_sage<64><<<2048, 256, 0, stream>>>(h1, row_ptr, col, inv, Wl1, bl1, Wr1, h2);
    k_sage<64><<<2048, 256, 0, stream>>>(h2, row_ptr, col, inv, Wl2, bl2, Wr2, h1);

    k_pool<<<256, 256, 0, stream>>>(h1, batch, pooled);
    k_head<<<1, 512, 0, stream>>>(pooled, Wout, bout, (float*)d_out);
}

// Round 2
// 751.719 us; speedup vs baseline: 1.1397x; 1.1397x over previous
//
#include <hip/hip_runtime.h>
#include <math.h>
#include <stdint.h>

#define N_NODES 100000
#define N_EDGES 1600000
#define N_GRAPHS 64

// ---------------- workspace layout (bytes) ----------------
// cnt     @ 0        : 100000 int
// fill    @ 400128   : 100000 int
// row_ptr @ 800256   : 100001 int
// col     @ 1200384  : 1600000 int (6.4 MB)
// pooled  @ 7600384  : 64*64 float
// bsum    @ 7616768  : 128 int
// M       @ 7617408  : 100000*64 float (25.6 MB)   mean / h (in-place)
// A       @ 33217408 : 100000*64 float (25.6 MB)
// total ~58.8 MB

__device__ __forceinline__ void atomicMaxFloat(float* addr, float val) {
    if (val >= 0.0f) {
        atomicMax((int*)addr, __float_as_int(val));
    } else {
        atomicMin((unsigned int*)addr, __float_as_uint(val));
    }
}

__global__ void k_init(int* __restrict__ cnt, int* __restrict__ fill,
                       float* __restrict__ pooled) {
    int i = blockIdx.x * blockDim.x + threadIdx.x;
    if (i < N_NODES) { cnt[i] = 0; fill[i] = 0; }
    if (i < N_GRAPHS * 64) pooled[i] = -INFINITY;
}

__global__ void k_hist(const int* __restrict__ dst, int* __restrict__ cnt) {
    int e = blockIdx.x * blockDim.x + threadIdx.x;
    if (e < N_EDGES) atomicAdd(&cnt[dst[e]], 1);
}

#define SCAN_CHUNK 1024

__global__ void k_scan1(const int* __restrict__ cnt, int* __restrict__ bsum) {
    __shared__ int lds[256];
    int b = blockIdx.x, t = threadIdx.x;
    int base = b * SCAN_CHUNK + t * 4;
    int s = 0;
#pragma unroll
    for (int j = 0; j < 4; ++j) {
        int i = base + j;
        if (i < N_NODES) s += cnt[i];
    }
    lds[t] = s;
    __syncthreads();
    for (int off = 128; off > 0; off >>= 1) {
        if (t < off) lds[t] += lds[t + off];
        __syncthreads();
    }
    if (t == 0) bsum[b] = lds[0];
}

__global__ void k_scan2(int* __restrict__ bsum, int nb) {
    if (threadIdx.x == 0 && blockIdx.x == 0) {
        int acc = 0;
        for (int i = 0; i < nb; ++i) { int v = bsum[i]; bsum[i] = acc; acc += v; }
    }
}

__global__ void k_scan3(const int* __restrict__ cnt, const int* __restrict__ bsum,
                        int* __restrict__ row_ptr) {
    __shared__ int lds[256];
    int b = blockIdx.x, t = threadIdx.x;
    int base = b * SCAN_CHUNK + t * 4;
    int v[4];
    int s = 0;
#pragma unroll
    for (int j = 0; j < 4; ++j) {
        int i = base + j;
        v[j] = (i < N_NODES) ? cnt[i] : 0;
        s += v[j];
    }
    lds[t] = s;
    __syncthreads();
    for (int off = 1; off < 256; off <<= 1) {
        int add = (t >= off) ? lds[t - off] : 0;
        __syncthreads();
        lds[t] += add;
        __syncthreads();
    }
    int ex = bsum[b] + ((t > 0) ? lds[t - 1] : 0);
#pragma unroll
    for (int j = 0; j < 4; ++j) {
        int i = base + j;
        if (i < N_NODES) { ex += v[j]; row_ptr[i + 1] = ex; }
    }
    if (b == 0 && t == 0) row_ptr[0] = 0;
}

__global__ void k_fill(const int* __restrict__ src, const int* __restrict__ dst,
                       const int* __restrict__ row_ptr, int* __restrict__ fill,
                       int* __restrict__ col) {
    int e = blockIdx.x * blockDim.x + threadIdx.x;
    if (e < N_EDGES) {
        int d = dst[e];
        int pos = atomicAdd(&fill[d], 1);
        col[row_ptr[d] + pos] = src[e];
    }
}

// ---------------------------------------------------------------------------
// Aggregation only: mean[node][0..FIN) (stride 64) = mean over neighbors of h
// One wave owns NC contiguous nodes; row_ptr for all of them loaded in ONE
// lane-parallel load. No LDS, low VGPR -> high occupancy, deep gather MLP.
// ---------------------------------------------------------------------------
#define NC 16

template <int FIN>
__global__ __launch_bounds__(256) void k_agg(
    const float* __restrict__ h, const int* __restrict__ row_ptr,
    const int* __restrict__ col, float* __restrict__ mean) {
    int lane = threadIdx.x & 63;
    int wave = blockIdx.x * 4 + (threadIdx.x >> 6);
    int base = wave * NC;
    if (base >= N_NODES) return;
    // lanes 0..NC hold row_ptr[base+lane]
    int rp = row_ptr[base + (lane < NC ? lane : NC)];

    for (int i = 0; i < NC; ++i) {
        int node = base + i;
        int start = __shfl(rp, i);
        int end   = __shfl(rp, i + 1);
        float s = 0.0f;

        if constexpr (FIN == 64) {
            for (int eb = start; eb < end; eb += 64) {
                int n = end - eb; if (n > 64) n = 64;
                int c = (eb + lane < end) ? col[eb + lane] : 0;
                int j = 0;
                for (; j + 7 < n; j += 8) {
                    int c0 = __shfl(c, j),     c1 = __shfl(c, j + 1);
                    int c2 = __shfl(c, j + 2), c3 = __shfl(c, j + 3);
                    int c4 = __shfl(c, j + 4), c5 = __shfl(c, j + 5);
                    int c6 = __shfl(c, j + 6), c7 = __shfl(c, j + 7);
                    float a0 = h[c0 * 64 + lane], a1 = h[c1 * 64 + lane];
                    float a2 = h[c2 * 64 + lane], a3 = h[c3 * 64 + lane];
                    float a4 = h[c4 * 64 + lane], a5 = h[c5 * 64 + lane];
                    float a6 = h[c6 * 64 + lane], a7 = h[c7 * 64 + lane];
                    s += ((a0 + a1) + (a2 + a3)) + ((a4 + a5) + (a6 + a7));
                }
                for (; j + 3 < n; j += 4) {
                    int c0 = __shfl(c, j),     c1 = __shfl(c, j + 1);
                    int c2 = __shfl(c, j + 2), c3 = __shfl(c, j + 3);
                    float a0 = h[c0 * 64 + lane], a1 = h[c1 * 64 + lane];
                    float a2 = h[c2 * 64 + lane], a3 = h[c3 * 64 + lane];
                    s += (a0 + a1) + (a2 + a3);
                }
                for (; j < n; ++j) {
                    int cc = __shfl(c, j);
                    s += h[cc * 64 + lane];
                }
            }
        } else {  // FIN == 32: halves of the wave take alternating edges
            int k = lane & 31;
            int half = lane >> 5;
            for (int eb = start; eb < end; eb += 64) {
                int n = end - eb; if (n > 64) n = 64;
                int c = (eb + lane < end) ? col[eb + lane] : 0;
                int j = 0;
                for (; j + 7 < n; j += 8) {
                    int c0 = __shfl(c, j + half);
                    int c1 = __shfl(c, j + 2 + half);
                    int c2 = __shfl(c, j + 4 + half);
                    int c3 = __shfl(c, j + 6 + half);
                    float a0 = h[c0 * 32 + k], a1 = h[c1 * 32 + k];
                    float a2 = h[c2 * 32 + k], a3 = h[c3 * 32 + k];
                    s += (a0 + a1) + (a2 + a3);
                }
                for (; j < n; j += 2) {
                    if (j + half < n) {
                        int cc = __shfl(c, j + half);
                        s += h[cc * 32 + k];
                    }
                }
            }
            s += __shfl_xor(s, 32);
        }

        int deg = end - start;
        float m = (deg > 0) ? s / (float)deg : 0.0f;
        if (FIN == 64 || lane < 32) mean[node * 64 + (FIN == 64 ? lane : (lane & 31))] = m;
    }
}

// ---------------------------------------------------------------------------
// Dense transform: out[node][f] = sum_k mean[node][k]*Wl[k][f]
//                              +  sum_k x[node][k]*Wr[k][f]  + bl[f]
// lane = output feature. Weights staged in LDS. May run IN-PLACE (out==mean):
// each wave reads its node's rows fully into registers before storing.
// ---------------------------------------------------------------------------
template <int FIN, int XS>
__global__ __launch_bounds__(256) void k_dense(
    const float* mean,  // stride 64, first FIN valid (no restrict: may alias out)
    const float* __restrict__ x,  // stride XS
    const float* __restrict__ Wl, const float* __restrict__ bl,
    const float* __restrict__ Wr, float* out) {
    __shared__ float wl[FIN * 64];
    __shared__ float wr[FIN * 64];
    for (int i = threadIdx.x; i < FIN * 16; i += 256) {
        ((float4*)wl)[i] = ((const float4*)Wl)[i];
        ((float4*)wr)[i] = ((const float4*)Wr)[i];
    }
    __syncthreads();

    int lane = threadIdx.x & 63;
    int wave = blockIdx.x * 4 + (threadIdx.x >> 6);
    int nWaves = gridDim.x * 4;
    float blf = bl[lane];

    for (int node = wave; node < N_NODES; node += nWaves) {
        float mr = mean[node * 64 + (FIN == 64 ? lane : (lane & 31))];
        float xr = x[node * XS + (XS == 64 ? lane : (lane & 31))];
        float acc = blf;
#pragma unroll
        for (int kk = 0; kk < FIN; ++kk) {
            float mk = __shfl(mr, kk);
            float xk = __shfl(xr, kk);
            acc += mk * wl[kk * 64 + lane] + xk * wr[kk * 64 + lane];
        }
        out[node * 64 + lane] = acc;
    }
}

__global__ __launch_bounds__(256) void k_pool(const float* __restrict__ h,
                                              const int* __restrict__ batch,
                                              float* __restrict__ pooled) {
    int lane = threadIdx.x & 63;
    int wave = (blockIdx.x * blockDim.x + threadIdx.x) >> 6;
    int nWaves = (gridDim.x * blockDim.x) >> 6;
    int per = (N_NODES + nWaves - 1) / nWaves;
    int beg = wave * per;
    int end = beg + per; if (end > N_NODES) end = N_NODES;
    if (beg >= end) return;
    int curg = batch[beg];
    float m = -INFINITY;
    for (int i = beg; i < end; ++i) {
        int g = batch[i];
        if (g != curg) {
            atomicMaxFloat(&pooled[curg * 64 + lane], m);
            m = -INFINITY;
            curg = g;
        }
        m = fmaxf(m, h[(size_t)i * 64 + lane]);
    }
    atomicMaxFloat(&pooled[curg * 64 + lane], m);
}

__global__ void k_head(const float* __restrict__ pooled,
                       const float* __restrict__ Wout,
                       const float* __restrict__ bout, float* __restrict__ out) {
    int tid = threadIdx.x;          // 512 threads: g = tid>>3, o = tid&7
    int g = tid >> 3, o = tid & 7;
    float acc = bout[o];
#pragma unroll
    for (int k = 0; k < 64; ++k) acc += pooled[g * 64 + k] * Wout[k * 8 + o];
    float mx = acc;
#pragma unroll
    for (int m = 1; m < 8; m <<= 1) mx = fmaxf(mx, __shfl_xor(mx, m));
    float ex = expf(acc - mx);
    float sum = ex;
#pragma unroll
    for (int m = 1; m < 8; m <<= 1) sum += __shfl_xor(sum, m);
    out[g * 8 + o] = (acc - mx) - logf(sum);
}

extern "C" void kernel_launch(void* const* d_in, const int* in_sizes, int n_in,
                              void* d_out, int out_size, void* d_ws, size_t ws_size,
                              hipStream_t stream) {
    const float* x    = (const float*)d_in[0];
    const float* Wl0  = (const float*)d_in[1];
    const float* bl0  = (const float*)d_in[2];
    const float* Wr0  = (const float*)d_in[3];
    const float* Wl1  = (const float*)d_in[4];
    const float* bl1  = (const float*)d_in[5];
    const float* Wr1  = (const float*)d_in[6];
    const float* Wl2  = (const float*)d_in[7];
    const float* bl2  = (const float*)d_in[8];
    const float* Wr2  = (const float*)d_in[9];
    const float* Wout = (const float*)d_in[10];
    const float* bout = (const float*)d_in[11];
    const int*   eidx = (const int*)d_in[12];
    const int*   batch= (const int*)d_in[13];
    const int* src = eidx;
    const int* dst = eidx + N_EDGES;

    uint8_t* ws = (uint8_t*)d_ws;
    int*   cnt     = (int*)(ws + 0);
    int*   fill    = (int*)(ws + 400128);
    int*   row_ptr = (int*)(ws + 800256);
    int*   col     = (int*)(ws + 1200384);
    float* pooled  = (float*)(ws + 7600384);
    int*   bsum    = (int*)(ws + 7616768);
    float* M       = (float*)(ws + 7617408);
    float* A       = (float*)(ws + 33217408);

    int nb = (N_NODES + SCAN_CHUNK - 1) / SCAN_CHUNK;  // 98

    k_init<<<(N_NODES + 255) / 256, 256, 0, stream>>>(cnt, fill, pooled);
    k_hist<<<(N_EDGES + 255) / 256, 256, 0, stream>>>(dst, cnt);
    k_scan1<<<nb, 256, 0, stream>>>(cnt, bsum);
    k_scan2<<<1, 64, 0, stream>>>(bsum, nb);
    k_scan3<<<nb, 256, 0, stream>>>(cnt, bsum, row_ptr);
    k_fill<<<(N_EDGES + 255) / 256, 256, 0, stream>>>(src, dst, row_ptr, fill, col);

    int aggBlocks = (N_NODES / NC + 3) / 4;  // 1563

    // layer 0: mean0 -> M (stride 64), h1 = dense in-place -> M
    k_agg<32><<<aggBlocks, 256, 0, stream>>>(x, row_ptr, col, M);
    k_dense<32, 32><<<2048, 256, 0, stream>>>(M, x, Wl0, bl0, Wr0, M);
    // layer 1: mean1 -> A, h2 in-place -> A
    k_agg<64><<<aggBlocks, 256, 0, stream>>>(M, row_ptr, col, A);
    k_dense<64, 64><<<2048, 256, 0, stream>>>(A, M, Wl1, bl1, Wr1, A);
    // layer 2: mean2 -> M, h3 in-place -> M
    k_agg<64><<<aggBlocks, 256, 0, stream>>>(A, row_ptr, col, M);
    k_dense<64, 64><<<2048, 256, 0, stream>>>(M, A, Wl2, bl2, Wr2, M);

    k_pool<<<256, 256, 0, stream>>>(M, batch, pooled);
    k_head<<<1, 512, 0, stream>>>(pooled, Wout, bout, (float*)d_out);
}

// Round 3
// 697.907 us; speedup vs baseline: 1.2276x; 1.0771x over previous
//
#include <hip/hip_runtime.h>
#include <math.h>
#include <stdint.h>

#define N_NODES 100000
#define N_EDGES 1600000
#define N_GRAPHS 64

// ---------------- workspace layout (bytes) ----------------
// cnt     @ 0        : 100000 int
// fill    @ 400128   : 100000 int
// row_ptr @ 800256   : 100001 int
// col     @ 1200384  : 1600000 int (6.4 MB)
// pooled  @ 7600384  : 64*64 float
// bsum    @ 7616768  : 128 int
// M       @ 7617408  : 100000*64 float (25.6 MB)   mean / h (in-place)
// A       @ 33217408 : 100000*64 float (25.6 MB)
// total ~58.8 MB

__device__ __forceinline__ void atomicMaxFloat(float* addr, float val) {
    if (val >= 0.0f) {
        atomicMax((int*)addr, __float_as_int(val));
    } else {
        atomicMin((unsigned int*)addr, __float_as_uint(val));
    }
}

__global__ void k_init(int* __restrict__ cnt, int* __restrict__ fill,
                       float* __restrict__ pooled) {
    int i = blockIdx.x * blockDim.x + threadIdx.x;
    if (i < N_NODES) { cnt[i] = 0; fill[i] = 0; }
    if (i < N_GRAPHS * 64) pooled[i] = -INFINITY;
}

__global__ void k_hist(const int* __restrict__ dst, int* __restrict__ cnt) {
    int e = blockIdx.x * blockDim.x + threadIdx.x;
    if (e < N_EDGES) atomicAdd(&cnt[dst[e]], 1);
}

#define SCAN_CHUNK 1024

__global__ void k_scan1(const int* __restrict__ cnt, int* __restrict__ bsum) {
    __shared__ int lds[256];
    int b = blockIdx.x, t = threadIdx.x;
    int base = b * SCAN_CHUNK + t * 4;
    int s = 0;
#pragma unroll
    for (int j = 0; j < 4; ++j) {
        int i = base + j;
        if (i < N_NODES) s += cnt[i];
    }
    lds[t] = s;
    __syncthreads();
    for (int off = 128; off > 0; off >>= 1) {
        if (t < off) lds[t] += lds[t + off];
        __syncthreads();
    }
    if (t == 0) bsum[b] = lds[0];
}

__global__ void k_scan2(int* __restrict__ bsum, int nb) {
    if (threadIdx.x == 0 && blockIdx.x == 0) {
        int acc = 0;
        for (int i = 0; i < nb; ++i) { int v = bsum[i]; bsum[i] = acc; acc += v; }
    }
}

__global__ void k_scan3(const int* __restrict__ cnt, const int* __restrict__ bsum,
                        int* __restrict__ row_ptr) {
    __shared__ int lds[256];
    int b = blockIdx.x, t = threadIdx.x;
    int base = b * SCAN_CHUNK + t * 4;
    int v[4];
    int s = 0;
#pragma unroll
    for (int j = 0; j < 4; ++j) {
        int i = base + j;
        v[j] = (i < N_NODES) ? cnt[i] : 0;
        s += v[j];
    }
    lds[t] = s;
    __syncthreads();
    for (int off = 1; off < 256; off <<= 1) {
        int add = (t >= off) ? lds[t - off] : 0;
        __syncthreads();
        lds[t] += add;
        __syncthreads();
    }
    int ex = bsum[b] + ((t > 0) ? lds[t - 1] : 0);
#pragma unroll
    for (int j = 0; j < 4; ++j) {
        int i = base + j;
        if (i < N_NODES) { ex += v[j]; row_ptr[i + 1] = ex; }
    }
    if (b == 0 && t == 0) row_ptr[0] = 0;
}

__global__ void k_fill(const int* __restrict__ src, const int* __restrict__ dst,
                       const int* __restrict__ row_ptr, int* __restrict__ fill,
                       int* __restrict__ col) {
    int e = blockIdx.x * blockDim.x + threadIdx.x;
    if (e < N_EDGES) {
        int d = dst[e];
        int pos = atomicAdd(&fill[d], 1);
        col[row_ptr[d] + pos] = src[e];
    }
}

// ---------------------------------------------------------------------------
// Aggregation only: mean[node][0..FIN) (stride 64) = mean over neighbors of h
// One wave owns NC contiguous nodes; row_ptr for all of them loaded in ONE
// lane-parallel load. No LDS, low VGPR -> high occupancy, deep gather MLP.
// ---------------------------------------------------------------------------
#define NC 16

template <int FIN>
__global__ __launch_bounds__(256) void k_agg(
    const float* __restrict__ h, const int* __restrict__ row_ptr,
    const int* __restrict__ col, float* __restrict__ mean) {
    int lane = threadIdx.x & 63;
    int wave = blockIdx.x * 4 + (threadIdx.x >> 6);
    int base = wave * NC;
    if (base >= N_NODES) return;
    // lanes 0..NC hold row_ptr[base+lane]
    int rp = row_ptr[base + (lane < NC ? lane : NC)];

    for (int i = 0; i < NC; ++i) {
        int node = base + i;
        int start = __shfl(rp, i);
        int end   = __shfl(rp, i + 1);
        float s = 0.0f;

        if constexpr (FIN == 64) {
            for (int eb = start; eb < end; eb += 64) {
                int n = end - eb; if (n > 64) n = 64;
                int c = (eb + lane < end) ? col[eb + lane] : 0;
                int j = 0;
                for (; j + 7 < n; j += 8) {
                    int c0 = __shfl(c, j),     c1 = __shfl(c, j + 1);
                    int c2 = __shfl(c, j + 2), c3 = __shfl(c, j + 3);
                    int c4 = __shfl(c, j + 4), c5 = __shfl(c, j + 5);
                    int c6 = __shfl(c, j + 6), c7 = __shfl(c, j + 7);
                    float a0 = h[c0 * 64 + lane], a1 = h[c1 * 64 + lane];
                    float a2 = h[c2 * 64 + lane], a3 = h[c3 * 64 + lane];
                    float a4 = h[c4 * 64 + lane], a5 = h[c5 * 64 + lane];
                    float a6 = h[c6 * 64 + lane], a7 = h[c7 * 64 + lane];
                    s += ((a0 + a1) + (a2 + a3)) + ((a4 + a5) + (a6 + a7));
                }
                for (; j + 3 < n; j += 4) {
                    int c0 = __shfl(c, j),     c1 = __shfl(c, j + 1);
                    int c2 = __shfl(c, j + 2), c3 = __shfl(c, j + 3);
                    float a0 = h[c0 * 64 + lane], a1 = h[c1 * 64 + lane];
                    float a2 = h[c2 * 64 + lane], a3 = h[c3 * 64 + lane];
                    s += (a0 + a1) + (a2 + a3);
                }
                for (; j < n; ++j) {
                    int cc = __shfl(c, j);
                    s += h[cc * 64 + lane];
                }
            }
        } else {  // FIN == 32: halves of the wave take alternating edges
            int k = lane & 31;
            int half = lane >> 5;
            for (int eb = start; eb < end; eb += 64) {
                int n = end - eb; if (n > 64) n = 64;
                int c = (eb + lane < end) ? col[eb + lane] : 0;
                int j = 0;
                for (; j + 7 < n; j += 8) {
                    int c0 = __shfl(c, j + half);
                    int c1 = __shfl(c, j + 2 + half);
                    int c2 = __shfl(c, j + 4 + half);
                    int c3 = __shfl(c, j + 6 + half);
                    float a0 = h[c0 * 32 + k], a1 = h[c1 * 32 + k];
                    float a2 = h[c2 * 32 + k], a3 = h[c3 * 32 + k];
                    s += (a0 + a1) + (a2 + a3);
                }
                for (; j < n; j += 2) {
                    if (j + half < n) {
                        int cc = __shfl(c, j + half);
                        s += h[cc * 32 + k];
                    }
                }
            }
            s += __shfl_xor(s, 32);
        }

        int deg = end - start;
        float m = (deg > 0) ? s / (float)deg : 0.0f;
        if (FIN == 64 || lane < 32) mean[node * 64 + (FIN == 64 ? lane : (lane & 31))] = m;
    }
}

// ---------------------------------------------------------------------------
// Dense transform: out[node][f] = sum_k mean[node][k]*Wl[k][f]
//                              +  sum_k x[node][k]*Wr[k][f]  + bl[f]
// lane = output feature. Weight COLUMNS live in VGPRs (coalesced preload).
// Node rows are read as uniform-address float4 loads (cache broadcast) -> the
// inner loop is pure VALU FMA: no LDS, no shuffles. 4 partial accumulators
// break the serial FMA chain. May run in-place (out == mean or x): each
// node's rows are fully consumed before its store.
// ---------------------------------------------------------------------------
template <int FIN, int XS>
__global__ __launch_bounds__(256) void k_dense(
    const float* mean,            // stride 64, first FIN valid (may alias out)
    const float* x,               // stride XS (may alias out)
    const float* __restrict__ Wl, const float* __restrict__ bl,
    const float* __restrict__ Wr, float* out) {
    int lane = threadIdx.x & 63;
    float wl[FIN], wr[FIN];
#pragma unroll
    for (int k = 0; k < FIN; ++k) {
        wl[k] = Wl[k * 64 + lane];   // coalesced: row k of Wl
        wr[k] = Wr[k * 64 + lane];
    }
    float blf = bl[lane];

    int wave = blockIdx.x * 4 + (threadIdx.x >> 6);
    int nWaves = gridDim.x * 4;

    for (int node = wave; node < N_NODES; node += nWaves) {
        const float4* mrow = (const float4*)(mean + (size_t)node * 64);
        const float4* xrow = (const float4*)(x + (size_t)node * XS);
        float a0 = blf, a1 = 0.0f, a2 = 0.0f, a3 = 0.0f;
#pragma unroll
        for (int q = 0; q < FIN / 4; ++q) {
            float4 m4 = mrow[q];
            a0 += m4.x * wl[4 * q + 0];
            a1 += m4.y * wl[4 * q + 1];
            a2 += m4.z * wl[4 * q + 2];
            a3 += m4.w * wl[4 * q + 3];
        }
#pragma unroll
        for (int q = 0; q < XS / 4; ++q) {
            float4 x4 = xrow[q];
            a0 += x4.x * wr[4 * q + 0];
            a1 += x4.y * wr[4 * q + 1];
            a2 += x4.z * wr[4 * q + 2];
            a3 += x4.w * wr[4 * q + 3];
        }
        out[(size_t)node * 64 + lane] = (a0 + a1) + (a2 + a3);
    }
}

__global__ __launch_bounds__(256) void k_pool(const float* __restrict__ h,
                                              const int* __restrict__ batch,
                                              float* __restrict__ pooled) {
    int lane = threadIdx.x & 63;
    int wave = (blockIdx.x * blockDim.x + threadIdx.x) >> 6;
    int nWaves = (gridDim.x * blockDim.x) >> 6;
    int per = (N_NODES + nWaves - 1) / nWaves;
    int beg = wave * per;
    int end = beg + per; if (end > N_NODES) end = N_NODES;
    if (beg >= end) return;
    int curg = batch[beg];
    float m = -INFINITY;
    for (int i = beg; i < end; ++i) {
        int g = batch[i];
        if (g != curg) {
            atomicMaxFloat(&pooled[curg * 64 + lane], m);
            m = -INFINITY;
            curg = g;
        }
        m = fmaxf(m, h[(size_t)i * 64 + lane]);
    }
    atomicMaxFloat(&pooled[curg * 64 + lane], m);
}

__global__ void k_head(const float* __restrict__ pooled,
                       const float* __restrict__ Wout,
                       const float* __restrict__ bout, float* __restrict__ out) {
    int tid = threadIdx.x;          // 512 threads: g = tid>>3, o = tid&7
    int g = tid >> 3, o = tid & 7;
    float acc = bout[o];
#pragma unroll
    for (int k = 0; k < 64; ++k) acc += pooled[g * 64 + k] * Wout[k * 8 + o];
    float mx = acc;
#pragma unroll
    for (int m = 1; m < 8; m <<= 1) mx = fmaxf(mx, __shfl_xor(mx, m));
    float ex = expf(acc - mx);
    float sum = ex;
#pragma unroll
    for (int m = 1; m < 8; m <<= 1) sum += __shfl_xor(sum, m);
    out[g * 8 + o] = (acc - mx) - logf(sum);
}

extern "C" void kernel_launch(void* const* d_in, const int* in_sizes, int n_in,
                              void* d_out, int out_size, void* d_ws, size_t ws_size,
                              hipStream_t stream) {
    const float* x    = (const float*)d_in[0];
    const float* Wl0  = (const float*)d_in[1];
    const float* bl0  = (const float*)d_in[2];
    const float* Wr0  = (const float*)d_in[3];
    const float* Wl1  = (const float*)d_in[4];
    const float* bl1  = (const float*)d_in[5];
    const float* Wr1  = (const float*)d_in[6];
    const float* Wl2  = (const float*)d_in[7];
    const float* bl2  = (const float*)d_in[8];
    const float* Wr2  = (const float*)d_in[9];
    const float* Wout = (const float*)d_in[10];
    const float* bout = (const float*)d_in[11];
    const int*   eidx = (const int*)d_in[12];
    const int*   batch= (const int*)d_in[13];
    const int* src = eidx;
    const int* dst = eidx + N_EDGES;

    uint8_t* ws = (uint8_t*)d_ws;
    int*   cnt     = (int*)(ws + 0);
    int*   fill    = (int*)(ws + 400128);
    int*   row_ptr = (int*)(ws + 800256);
    int*   col     = (int*)(ws + 1200384);
    float* pooled  = (float*)(ws + 7600384);
    int*   bsum    = (int*)(ws + 7616768);
    float* M       = (float*)(ws + 7617408);
    float* A       = (float*)(ws + 33217408);

    int nb = (N_NODES + SCAN_CHUNK - 1) / SCAN_CHUNK;  // 98

    k_init<<<(N_NODES + 255) / 256, 256, 0, stream>>>(cnt, fill, pooled);
    k_hist<<<(N_EDGES + 255) / 256, 256, 0, stream>>>(dst, cnt);
    k_scan1<<<nb, 256, 0, stream>>>(cnt, bsum);
    k_scan2<<<1, 64, 0, stream>>>(bsum, nb);
    k_scan3<<<nb, 256, 0, stream>>>(cnt, bsum, row_ptr);
    k_fill<<<(N_EDGES + 255) / 256, 256, 0, stream>>>(src, dst, row_ptr, fill, col);

    int aggBlocks = (N_NODES / NC + 3) / 4;  // 1563

    // layer 0: mean0 -> M (stride 64), h1 = dense in-place -> M
    k_agg<32><<<aggBlocks, 256, 0, stream>>>(x, row_ptr, col, M);
    k_dense<32, 32><<<2048, 256, 0, stream>>>(M, x, Wl0, bl0, Wr0, M);
    // layer 1: mean1 -> A, h2 in-place -> A
    k_agg<64><<<aggBlocks, 256, 0, stream>>>(M, row_ptr, col, A);
    k_dense<64, 64><<<2048, 256, 0, stream>>>(A, M, Wl1, bl1, Wr1, A);
    // layer 2: mean2 -> M, h3 in-place -> M
    k_agg<64><<<aggBlocks, 256, 0, stream>>>(A, row_ptr, col, M);
    k_dense<64, 64><<<2048, 256, 0, stream>>>(M, A, Wl2, bl2, Wr2, M);

    k_pool<<<256, 256, 0, stream>>>(M, batch, pooled);
    k_head<<<1, 512, 0, stream>>>(pooled, Wout, bout, (float*)d_out);
}